// Round 1
// baseline (5905.935 us; speedup 1.0000x reference)
//
#include <hip/hip_runtime.h>
#include <cmath>

#define NFEAT 350
#define DMODEL 512
#define NLAYER 4
#define DSZ 64
#define REG_E 32
#define BATCH 32
#define SEQ 2048
#define MTOK (BATCH * SEQ)      // 65536
#define KCOMB (NFEAT + REG_E)   // 382
#define CLAMP_V 20.0f

// ---------------- tiled f32 GEMM: C = epilogue(A_loader @ B + bias) ----------------
// TM=64, TN=64, TK=16, 256 threads, 4x4 microtile per thread.
// MODE 0: A = concat(x, emb[rid]) (K=382), epilogue elu        -> hidden
// MODE 1: A = hidden (K=512), epilogue +bias (N=350)           -> logits
// MODE 2: A = x * weights (K=350), epilogue +bias              -> h
// MODE 3: A = LN(h) on the fly (K=512), N=256 (4 gates), gate epilogue -> gates
struct GemmArgs {
    const float* A;
    const float* B;
    const float* bias;
    float* C;
    int K, N;
    const float* x;
    const int* rid;
    const float* emb;
    const float* wgt;
    const float* mu;
    const float* rstd;
    const float* lng;
    const float* lnb;
    const float* B1; const float* B2; const float* B3;       // wf, wz, wo
    const float* bi1; const float* bi2; const float* bi3;    // bf, bz, bo
};

template <int MODE>
__global__ __launch_bounds__(256) void gemm_k(GemmArgs a) {
    __shared__ float As[16][64];
    __shared__ float Bs[16][64];
    const int tid = threadIdx.x;
    const int tx = tid & 15;
    const int ty = tid >> 4;
    const int row0 = blockIdx.y * 64;
    const int n0 = blockIdx.x * 64;

    const float* Bsel = a.B;
    const float* bsel = a.bias;
    if (MODE == 3) {
        int g = blockIdx.x;
        if (g == 1) { Bsel = a.B1; bsel = a.bi1; }
        else if (g == 2) { Bsel = a.B2; bsel = a.bi2; }
        else if (g == 3) { Bsel = a.B3; bsel = a.bi3; }
    }

    float acc[4][4] = {};

    for (int k0 = 0; k0 < a.K; k0 += 16) {
        // A tile: 64 rows x 16 k. consecutive tid -> consecutive k (64B segments)
        {
            int kk = tid & 15;
            int mm = tid >> 4;
            int gk = k0 + kk;
#pragma unroll
            for (int i = 0; i < 4; i++) {
                int m = mm + i * 16;
                int grow = row0 + m;
                float v = 0.f;
                if (MODE == 0) {
                    if (gk < KCOMB) {
                        if (gk < NFEAT) v = a.x[(size_t)grow * NFEAT + gk];
                        else v = a.emb[a.rid[grow] * REG_E + (gk - NFEAT)];
                    }
                } else if (MODE == 1) {
                    v = a.A[(size_t)grow * DMODEL + gk];
                } else if (MODE == 2) {
                    if (gk < NFEAT)
                        v = a.x[(size_t)grow * NFEAT + gk] * a.wgt[(size_t)grow * NFEAT + gk];
                } else {
                    float hv = a.A[(size_t)grow * DMODEL + gk];
                    v = (hv - a.mu[grow]) * a.rstd[grow] * a.lng[gk] + a.lnb[gk];
                }
                As[kk][m] = v;
            }
        }
        // B tile: 16 k x 64 n. consecutive tid -> consecutive n (256B)
        {
            int nn = tid & 63;
            int kk4 = tid >> 6;
#pragma unroll
            for (int i = 0; i < 4; i++) {
                int kk = kk4 + i * 4;
                int gk = k0 + kk;
                int gn = n0 + nn;
                float v = 0.f;
                if (MODE == 3) {
                    v = Bsel[gk * DSZ + nn];
                } else {
                    if (gk < a.K && gn < a.N) v = a.B[(size_t)gk * a.N + gn];
                }
                Bs[kk][nn] = v;
            }
        }
        __syncthreads();
#pragma unroll
        for (int kk = 0; kk < 16; kk++) {
            float av[4], bv[4];
#pragma unroll
            for (int i = 0; i < 4; i++) av[i] = As[kk][ty * 4 + i];
#pragma unroll
            for (int j = 0; j < 4; j++) bv[j] = Bs[kk][tx * 4 + j];
#pragma unroll
            for (int i = 0; i < 4; i++)
#pragma unroll
                for (int j = 0; j < 4; j++) acc[i][j] += av[i] * bv[j];
        }
        __syncthreads();
    }

#pragma unroll
    for (int i = 0; i < 4; i++) {
        int grow = row0 + ty * 4 + i;
#pragma unroll
        for (int j = 0; j < 4; j++) {
            int gn = n0 + tx * 4 + j;
            if (gn >= a.N) continue;
            float v = acc[i][j] + bsel[MODE == 3 ? (gn & 63) : gn];
            if (MODE == 0) v = v > 0.f ? v : expm1f(v);
            if (MODE == 3) {
                int g = gn >> 6;
                if (g < 2) v = fminf(fmaxf(v, -CLAMP_V), CLAMP_V);
                else if (g == 2) v = tanhf(v);
                else v = 1.f / (1.f + expf(-v));
            }
            a.C[(size_t)grow * a.N + gn] = v;
        }
    }
}

// ---------------- per-token LN stats (mu, rstd) over 512 dims ----------------
__global__ __launch_bounds__(256) void ln_stats_k(const float* __restrict__ h,
                                                  float* __restrict__ mu,
                                                  float* __restrict__ rstd) {
    int tok = blockIdx.x * 4 + (threadIdx.x >> 6);
    int lane = threadIdx.x & 63;
    const float* row = h + (size_t)tok * DMODEL;
    float s = 0.f, sq = 0.f;
#pragma unroll
    for (int i = 0; i < 8; i++) {
        float v = row[lane + 64 * i];
        s += v;
        sq += v * v;
    }
#pragma unroll
    for (int o = 32; o > 0; o >>= 1) {
        s += __shfl_xor(s, o, 64);
        sq += __shfl_xor(sq, o, 64);
    }
    if (lane == 0) {
        float m = s * (1.f / DMODEL);
        float var = sq * (1.f / DMODEL) - m * m;
        mu[tok] = m;
        rstd[tok] = rsqrtf(var + 1e-5f);
    }
}

// ---------------- row softmax over 350, in place; also emit weights[:, -1, :] ----------------
__global__ __launch_bounds__(256) void softmax_k(float* __restrict__ wbuf,
                                                 float* __restrict__ out_wlast) {
    int tok = blockIdx.x * 4 + (threadIdx.x >> 6);
    int lane = threadIdx.x & 63;
    float* row = wbuf + (size_t)tok * NFEAT;
    float v[6];
    float mx = -1e30f;
#pragma unroll
    for (int i = 0; i < 6; i++) {
        int idx = lane + 64 * i;
        v[i] = (idx < NFEAT) ? row[idx] : -1e30f;
        mx = fmaxf(mx, v[i]);
    }
#pragma unroll
    for (int o = 32; o > 0; o >>= 1) mx = fmaxf(mx, __shfl_xor(mx, o, 64));
    float s = 0.f;
#pragma unroll
    for (int i = 0; i < 6; i++) {
        v[i] = expf(v[i] - mx);
        s += v[i];
    }
#pragma unroll
    for (int o = 32; o > 0; o >>= 1) s += __shfl_xor(s, o, 64);
    float inv = 1.f / s;
#pragma unroll
    for (int i = 0; i < 6; i++) {
        int idx = lane + 64 * i;
        if (idx < NFEAT) row[idx] = v[i] * inv;
    }
    if ((tok % SEQ) == SEQ - 1) {
        int b = tok / SEQ;
#pragma unroll
        for (int i = 0; i < 6; i++) {
            int idx = lane + 64 * i;
            if (idx < NFEAT) out_wlast[b * NFEAT + idx] = v[i] * inv;
        }
    }
}

// ---------------- sequential stabilized scan: 1 wave per batch row ----------------
__global__ __launch_bounds__(64) void scan_k(const float* __restrict__ gates,
                                             float* __restrict__ hs) {
    int b = blockIdx.x;
    int e = threadIdx.x;
    const float* gp = gates + (size_t)b * SEQ * 256;
    float* hp = hs + (size_t)b * SEQ * DSZ;
    float m = 0.f, c = 0.f;
    float li = gp[e], lf = gp[64 + e], z = gp[128 + e], o = gp[192 + e];
    for (int s = 0; s < SEQ; s++) {
        float nli = 0.f, nlf = 0.f, nz = 0.f, no = 0.f;
        if (s + 1 < SEQ) {
            const float* q = gp + (size_t)(s + 1) * 256;
            nli = q[e]; nlf = q[64 + e]; nz = q[128 + e]; no = q[192 + e];
        }
        float mlf = m + lf;
        float mn = fmaxf(mlf, li);
        float i_s = expf(li - mn);
        float f_s = expf(mlf - mn);
        c = f_s * c + i_s * z;
        m = mn;
        hp[(size_t)s * DSZ + e] = o * tanhf(c);
        li = nli; lf = nlf; z = nz; o = no;
    }
}

// ---------------- out-proj (hs@Wp+bp) + residual + LN, in-place on h ----------------
// 256 threads, 16 tokens/block (4 waves x 4 tokens), Wp staged in LDS.
__global__ __launch_bounds__(256) void outproj_k(const float* __restrict__ hs,
                                                 const float* __restrict__ wp,
                                                 const float* __restrict__ bp,
                                                 const float* __restrict__ nmg,
                                                 const float* __restrict__ nmb,
                                                 float* __restrict__ h) {
    __shared__ float shs[16][DSZ];     // 4 KB
    __shared__ float swp[16][DMODEL];  // 32 KB
    int wv = threadIdx.x >> 6;
    int lane = threadIdx.x & 63;
    int tok0 = blockIdx.x * 16;

    {   // 16 hs rows are contiguous: vector copy
        const float4* src = (const float4*)(hs + (size_t)tok0 * DSZ);
        ((float4*)&shs[0][0])[threadIdx.x] = src[threadIdx.x];
    }
    __syncthreads();

    float acc[4][8] = {};
    for (int k0 = 0; k0 < DSZ; k0 += 16) {
        const float4* src = (const float4*)(wp + (size_t)k0 * DMODEL);
#pragma unroll
        for (int i = 0; i < 8; i++)
            ((float4*)&swp[0][0])[threadIdx.x + i * 256] = src[threadIdx.x + i * 256];
        __syncthreads();
#pragma unroll
        for (int k = 0; k < 16; k++) {
            float bv[8];
#pragma unroll
            for (int j = 0; j < 8; j++) bv[j] = swp[k][lane + 64 * j];
#pragma unroll
            for (int t = 0; t < 4; t++) {
                float av = shs[wv * 4 + t][k0 + k];
#pragma unroll
                for (int j = 0; j < 8; j++) acc[t][j] += av * bv[j];
            }
        }
        __syncthreads();
    }

#pragma unroll
    for (int t = 0; t < 4; t++) {
        int tok = tok0 + wv * 4 + t;
        float u[8];
        float s = 0.f, sq = 0.f;
#pragma unroll
        for (int j = 0; j < 8; j++) {
            int col = lane + 64 * j;
            float v = h[(size_t)tok * DMODEL + col] + acc[t][j] + bp[col];
            u[j] = v;
            s += v;
            sq += v * v;
        }
#pragma unroll
        for (int o = 32; o > 0; o >>= 1) {
            s += __shfl_xor(s, o, 64);
            sq += __shfl_xor(sq, o, 64);
        }
        float mean = s * (1.f / DMODEL);
        float var = sq * (1.f / DMODEL) - mean * mean;
        float rs = rsqrtf(var + 1e-5f);
#pragma unroll
        for (int j = 0; j < 8; j++) {
            int col = lane + 64 * j;
            h[(size_t)tok * DMODEL + col] = (u[j] - mean) * rs * nmg[col] + nmb[col];
        }
    }
}

// ---------------- heads on h[:, -1, :] ----------------
__global__ __launch_bounds__(64) void heads_k(const float* __restrict__ h,
                                              const float* hd15_w, const float* hd15_b,
                                              const float* hd30_w, const float* hd30_b,
                                              const float* hv_w, const float* hv_b,
                                              const float* hreg_w, const float* hreg_b,
                                              const float* hrng_w, const float* hrng_b,
                                              float* __restrict__ out) {
    int b = blockIdx.x;
    int lane = threadIdx.x;
    __shared__ float row[DMODEL];
    const float* hp = h + (size_t)(b * SEQ + SEQ - 1) * DMODEL;
#pragma unroll
    for (int i = 0; i < 8; i++) row[lane + 64 * i] = hp[lane + 64 * i];
    __syncthreads();
#pragma unroll
    for (int i = 0; i < 8; i++) out[448 + b * DMODEL + lane + 64 * i] = row[lane + 64 * i];
    if (lane < 14) {
        const float* w; const float* bb;
        int ncol, j, off;
        if (lane == 0)      { w = hd15_w; bb = hd15_b; ncol = 1; j = 0;         off = 0 + b; }
        else if (lane == 1) { w = hd30_w; bb = hd30_b; ncol = 1; j = 0;         off = 32 + b; }
        else if (lane < 5)  { j = lane - 2;  w = hv_w;   bb = hv_b;   ncol = 3; off = 64 + b * 3 + j; }
        else if (lane < 11) { j = lane - 5;  w = hreg_w; bb = hreg_b; ncol = 6; off = 160 + b * 6 + j; }
        else                { j = lane - 11; w = hrng_w; bb = hrng_b; ncol = 3; off = 352 + b * 3 + j; }
        float s = bb[j];
        for (int k = 0; k < DMODEL; k++) s += row[k] * w[k * ncol + j];
        out[off] = s;
    }
}

extern "C" void kernel_launch(void* const* d_in, const int* in_sizes, int n_in,
                              void* d_out, int out_size, void* d_ws, size_t ws_size,
                              hipStream_t stream) {
    (void)in_sizes; (void)n_in; (void)out_size; (void)ws_size;
    const float* x      = (const float*)d_in[0];
    const int*   rid    = (const int*)d_in[1];
    const float* emb    = (const float*)d_in[2];
    const float* grn_w1 = (const float*)d_in[3];
    const float* grn_b1 = (const float*)d_in[4];
    const float* grn_w2 = (const float*)d_in[5];
    const float* grn_b2 = (const float*)d_in[6];
    const float* in_w   = (const float*)d_in[7];
    const float* in_b   = (const float*)d_in[8];
    const float* ln_g   = (const float*)d_in[9];
    const float* ln_b   = (const float*)d_in[10];
    const float* wi     = (const float*)d_in[11];
    const float* bi     = (const float*)d_in[12];
    const float* wf     = (const float*)d_in[13];
    const float* bf     = (const float*)d_in[14];
    const float* wz     = (const float*)d_in[15];
    const float* bz     = (const float*)d_in[16];
    const float* wo     = (const float*)d_in[17];
    const float* bo     = (const float*)d_in[18];
    const float* wp     = (const float*)d_in[19];
    const float* bp     = (const float*)d_in[20];
    const float* nm_g   = (const float*)d_in[21];
    const float* nm_b   = (const float*)d_in[22];

    float* out = (float*)d_out;
    float* ws = (float*)d_ws;

    // workspace layout (floats):
    // region A: h / hidden alias (hidden dead after GEMM2)      33,554,432
    // region B: weights(22,937,600) then gates(16,777,216)+hs(4,194,304)
    // region C: mu(65,536), rstd(65,536)
    float* h      = ws;
    float* hidden = ws;                       // alias: hidden dead before h is written
    float* wbuf   = ws + 33554432;            // logits -> weights (in place)
    float* gates  = wbuf;                     // reused after weights are dead
    float* hsbuf  = wbuf + 16777216;
    float* mu     = wbuf + 22937600;
    float* rstd   = mu + 65536;

    GemmArgs a = {};
    a.x = x; a.rid = rid; a.emb = emb;

    // GEMM 0: hidden = elu(concat(x, emb[rid]) @ grn_w1 + grn_b1)
    a.B = grn_w1; a.bias = grn_b1; a.C = hidden; a.K = KCOMB; a.N = DMODEL;
    gemm_k<0><<<dim3(8, MTOK / 64), 256, 0, stream>>>(a);

    // GEMM 1: logits = hidden @ grn_w2 + grn_b2
    a.A = hidden; a.B = grn_w2; a.bias = grn_b2; a.C = wbuf; a.K = DMODEL; a.N = NFEAT;
    gemm_k<1><<<dim3(6, MTOK / 64), 256, 0, stream>>>(a);

    // softmax in place + emit weights[:, -1, :]
    softmax_k<<<MTOK / 4, 256, 0, stream>>>(wbuf, out + 16832);

    // GEMM 2: h = (x * weights) @ in_w + in_b
    a.wgt = wbuf; a.B = in_w; a.bias = in_b; a.C = h; a.K = NFEAT; a.N = DMODEL;
    gemm_k<2><<<dim3(8, MTOK / 64), 256, 0, stream>>>(a);

    for (int l = 0; l < NLAYER; l++) {
        ln_stats_k<<<MTOK / 4, 256, 0, stream>>>(h, mu, rstd);

        GemmArgs g = {};
        g.A = h; g.K = DMODEL; g.N = 256; g.C = gates;
        g.mu = mu; g.rstd = rstd;
        g.lng = ln_g + l * DMODEL; g.lnb = ln_b + l * DMODEL;
        g.B  = wi + (size_t)l * DMODEL * DSZ; g.bias = bi + l * DSZ;
        g.B1 = wf + (size_t)l * DMODEL * DSZ; g.bi1  = bf + l * DSZ;
        g.B2 = wz + (size_t)l * DMODEL * DSZ; g.bi2  = bz + l * DSZ;
        g.B3 = wo + (size_t)l * DMODEL * DSZ; g.bi3  = bo + l * DSZ;
        gemm_k<3><<<dim3(4, MTOK / 64), 256, 0, stream>>>(g);

        scan_k<<<BATCH, 64, 0, stream>>>(gates, hsbuf);

        outproj_k<<<MTOK / 16, 256, 0, stream>>>(hsbuf,
                                                 wp + (size_t)l * DSZ * DMODEL,
                                                 bp + l * DMODEL,
                                                 nm_g + l * DMODEL,
                                                 nm_b + l * DMODEL,
                                                 h);
    }

    heads_k<<<BATCH, 64, 0, stream>>>(h,
                                      (const float*)d_in[23], (const float*)d_in[24],
                                      (const float*)d_in[25], (const float*)d_in[26],
                                      (const float*)d_in[27], (const float*)d_in[28],
                                      (const float*)d_in[29], (const float*)d_in[30],
                                      (const float*)d_in[31], (const float*)d_in[32],
                                      out);
}

// Round 2
// 3701.852 us; speedup vs baseline: 1.5954x; 1.5954x over previous
//
#include <hip/hip_runtime.h>
#include <cmath>

#define NFEAT 350
#define DMODEL 512
#define NLAYER 4
#define DSZ 64
#define REG_E 32
#define BATCH 32
#define SEQ 2048
#define MTOK (BATCH * SEQ)      // 65536
#define KCOMB (NFEAT + REG_E)   // 382
#define CLAMP_V 20.0f

#define CHUNK 64                // scan chunk length
#define NCHUNK (SEQ / CHUNK)    // 32 chunks per chain

// ---------------- tiled f32 GEMM: C = epilogue(A_loader @ B + bias) ----------------
// TM=64, TN=64, TK=16, 256 threads, 4x4 microtile per thread.
// MODE 0: A = concat(x, emb[rid]) (K=382), epilogue elu        -> hidden
// MODE 1: A = hidden (K=512), epilogue +bias (N=350)           -> logits
// MODE 2: A = x * weights (K=350), epilogue +bias              -> h
// MODE 3: A = LN(h) on the fly (K=512), N=256 (4 gates), gate epilogue -> gates
struct GemmArgs {
    const float* A;
    const float* B;
    const float* bias;
    float* C;
    int K, N;
    const float* x;
    const int* rid;
    const float* emb;
    const float* wgt;
    const float* mu;
    const float* rstd;
    const float* lng;
    const float* lnb;
    const float* B1; const float* B2; const float* B3;       // wf, wz, wo
    const float* bi1; const float* bi2; const float* bi3;    // bf, bz, bo
};

template <int MODE>
__global__ __launch_bounds__(256) void gemm_k(GemmArgs a) {
    __shared__ float As[16][64];
    __shared__ float Bs[16][64];
    const int tid = threadIdx.x;
    const int tx = tid & 15;
    const int ty = tid >> 4;
    const int row0 = blockIdx.y * 64;
    const int n0 = blockIdx.x * 64;

    const float* Bsel = a.B;
    const float* bsel = a.bias;
    if (MODE == 3) {
        int g = blockIdx.x;
        if (g == 1) { Bsel = a.B1; bsel = a.bi1; }
        else if (g == 2) { Bsel = a.B2; bsel = a.bi2; }
        else if (g == 3) { Bsel = a.B3; bsel = a.bi3; }
    }

    float acc[4][4] = {};

    for (int k0 = 0; k0 < a.K; k0 += 16) {
        {
            int kk = tid & 15;
            int mm = tid >> 4;
            int gk = k0 + kk;
#pragma unroll
            for (int i = 0; i < 4; i++) {
                int m = mm + i * 16;
                int grow = row0 + m;
                float v = 0.f;
                if (MODE == 0) {
                    if (gk < KCOMB) {
                        if (gk < NFEAT) v = a.x[(size_t)grow * NFEAT + gk];
                        else v = a.emb[a.rid[grow] * REG_E + (gk - NFEAT)];
                    }
                } else if (MODE == 1) {
                    v = a.A[(size_t)grow * DMODEL + gk];
                } else if (MODE == 2) {
                    if (gk < NFEAT)
                        v = a.x[(size_t)grow * NFEAT + gk] * a.wgt[(size_t)grow * NFEAT + gk];
                } else {
                    float hv = a.A[(size_t)grow * DMODEL + gk];
                    v = (hv - a.mu[grow]) * a.rstd[grow] * a.lng[gk] + a.lnb[gk];
                }
                As[kk][m] = v;
            }
        }
        {
            int nn = tid & 63;
            int kk4 = tid >> 6;
#pragma unroll
            for (int i = 0; i < 4; i++) {
                int kk = kk4 + i * 4;
                int gk = k0 + kk;
                int gn = n0 + nn;
                float v = 0.f;
                if (MODE == 3) {
                    v = Bsel[gk * DSZ + nn];
                } else {
                    if (gk < a.K && gn < a.N) v = a.B[(size_t)gk * a.N + gn];
                }
                Bs[kk][nn] = v;
            }
        }
        __syncthreads();
#pragma unroll
        for (int kk = 0; kk < 16; kk++) {
            float av[4], bv[4];
#pragma unroll
            for (int i = 0; i < 4; i++) av[i] = As[kk][ty * 4 + i];
#pragma unroll
            for (int j = 0; j < 4; j++) bv[j] = Bs[kk][tx * 4 + j];
#pragma unroll
            for (int i = 0; i < 4; i++)
#pragma unroll
                for (int j = 0; j < 4; j++) acc[i][j] += av[i] * bv[j];
        }
        __syncthreads();
    }

#pragma unroll
    for (int i = 0; i < 4; i++) {
        int grow = row0 + ty * 4 + i;
#pragma unroll
        for (int j = 0; j < 4; j++) {
            int gn = n0 + tx * 4 + j;
            if (gn >= a.N) continue;
            float v = acc[i][j] + bsel[MODE == 3 ? (gn & 63) : gn];
            if (MODE == 0) v = v > 0.f ? v : expm1f(v);
            if (MODE == 3) {
                int g = gn >> 6;
                if (g < 2) v = fminf(fmaxf(v, -CLAMP_V), CLAMP_V);
                else if (g == 2) v = tanhf(v);
                else v = 1.f / (1.f + expf(-v));
            }
            a.C[(size_t)grow * a.N + gn] = v;
        }
    }
}

// ---------------- per-token LN stats (mu, rstd) over 512 dims (layer 0 only) ----------------
__global__ __launch_bounds__(256) void ln_stats_k(const float* __restrict__ h,
                                                  float* __restrict__ mu,
                                                  float* __restrict__ rstd) {
    int tok = blockIdx.x * 4 + (threadIdx.x >> 6);
    int lane = threadIdx.x & 63;
    const float* row = h + (size_t)tok * DMODEL;
    float s = 0.f, sq = 0.f;
#pragma unroll
    for (int i = 0; i < 8; i++) {
        float v = row[lane + 64 * i];
        s += v;
        sq += v * v;
    }
#pragma unroll
    for (int o = 32; o > 0; o >>= 1) {
        s += __shfl_xor(s, o, 64);
        sq += __shfl_xor(sq, o, 64);
    }
    if (lane == 0) {
        float m = s * (1.f / DMODEL);
        float var = sq * (1.f / DMODEL) - m * m;
        mu[tok] = m;
        rstd[tok] = rsqrtf(var + 1e-5f);
    }
}

// ---------------- row softmax over 350, in place; also emit weights[:, -1, :] ----------------
__global__ __launch_bounds__(256) void softmax_k(float* __restrict__ wbuf,
                                                 float* __restrict__ out_wlast) {
    int tok = blockIdx.x * 4 + (threadIdx.x >> 6);
    int lane = threadIdx.x & 63;
    float* row = wbuf + (size_t)tok * NFEAT;
    float v[6];
    float mx = -1e30f;
#pragma unroll
    for (int i = 0; i < 6; i++) {
        int idx = lane + 64 * i;
        v[i] = (idx < NFEAT) ? row[idx] : -1e30f;
        mx = fmaxf(mx, v[i]);
    }
#pragma unroll
    for (int o = 32; o > 0; o >>= 1) mx = fmaxf(mx, __shfl_xor(mx, o, 64));
    float s = 0.f;
#pragma unroll
    for (int i = 0; i < 6; i++) {
        v[i] = expf(v[i] - mx);
        s += v[i];
    }
#pragma unroll
    for (int o = 32; o > 0; o >>= 1) s += __shfl_xor(s, o, 64);
    float inv = 1.f / s;
#pragma unroll
    for (int i = 0; i < 6; i++) {
        int idx = lane + 64 * i;
        if (idx < NFEAT) row[idx] = v[i] * inv;
    }
    if ((tok % SEQ) == SEQ - 1) {
        int b = tok / SEQ;
#pragma unroll
        for (int i = 0; i < 6; i++) {
            int idx = lane + 64 * i;
            if (idx < NFEAT) out_wlast[b * NFEAT + idx] = v[i] * inv;
        }
    }
}

// ================= chunked parallel scan =================
// Segment transform (F, L, s):  m' = max(m+F, L); c' = e^{m+F-m'} c + e^{L-m'} s.
// Phase A: per-chunk aggregates. block = (b, group of 4 chunks), 256 threads (chunk, e).
__global__ __launch_bounds__(256) void seg_agg_k(const float* __restrict__ gates,
                                                 float* __restrict__ aggF,
                                                 float* __restrict__ aggL,
                                                 float* __restrict__ aggS) {
    int b = blockIdx.x >> 3;
    int cg = blockIdx.x & 7;
    int chunk = cg * 4 + (threadIdx.x >> 6);
    int e = threadIdx.x & 63;
    const float* gp = gates + ((size_t)b * SEQ + (size_t)chunk * CHUNK) * 256;

    float F = 0.f, L = -1e30f, s = 0.f;
#pragma unroll 4
    for (int t = 0; t < CHUNK; t++) {
        const float* q = gp + (size_t)t * 256;
        float li = q[e], lf = q[64 + e], z = q[128 + e];
        float Ln = fmaxf(L + lf, li);
        s = expf(L + lf - Ln) * s + expf(li - Ln) * z;
        L = Ln;
        F += lf;
    }
    int idx = (b * NCHUNK + chunk) * 64 + e;
    aggF[idx] = F;
    aggL[idx] = L;
    aggS[idx] = s;
}

// Phase B: exclusive scan of chunk aggregates per chain -> incoming (m, c) per chunk.
// block = b, 64 threads (e).
__global__ __launch_bounds__(64) void chunk_scan_k(const float* __restrict__ aggF,
                                                   const float* __restrict__ aggL,
                                                   const float* __restrict__ aggS,
                                                   float* __restrict__ stM,
                                                   float* __restrict__ stC) {
    int b = blockIdx.x;
    int e = threadIdx.x;
    float m = 0.f, c = 0.f;
    for (int k = 0; k < NCHUNK; k++) {
        int idx = (b * NCHUNK + k) * 64 + e;
        stM[idx] = m;
        stC[idx] = c;
        float F = aggF[idx], L = aggL[idx], s = aggS[idx];
        float mn = fmaxf(m + F, L);
        c = expf(m + F - mn) * c + expf(L - mn) * s;
        m = mn;
    }
}

// Phase C: replay each chunk from its incoming state, emitting h = o * tanh(c).
__global__ __launch_bounds__(256) void replay_k(const float* __restrict__ gates,
                                                const float* __restrict__ stM,
                                                const float* __restrict__ stC,
                                                float* __restrict__ hs) {
    int b = blockIdx.x >> 3;
    int cg = blockIdx.x & 7;
    int chunk = cg * 4 + (threadIdx.x >> 6);
    int e = threadIdx.x & 63;
    int s0 = chunk * CHUNK;
    const float* gp = gates + ((size_t)b * SEQ + s0) * 256;
    float* hp = hs + ((size_t)b * SEQ + s0) * DSZ;

    int idx = (b * NCHUNK + chunk) * 64 + e;
    float m = stM[idx], c = stC[idx];
#pragma unroll 4
    for (int t = 0; t < CHUNK; t++) {
        const float* q = gp + (size_t)t * 256;
        float li = q[e], lf = q[64 + e], z = q[128 + e], o = q[192 + e];
        float mlf = m + lf;
        float mn = fmaxf(mlf, li);
        c = expf(mlf - mn) * c + expf(li - mn) * z;
        m = mn;
        hp[(size_t)t * DSZ + e] = o * tanhf(c);
    }
}

// ---------------- out-proj (hs@Wp+bp) + residual + LN, in-place on h ----------------
// Also emits mu/rstd of the NEW h (consumed by the next layer's gates GEMM).
__global__ __launch_bounds__(256) void outproj_k(const float* __restrict__ hs,
                                                 const float* __restrict__ wp,
                                                 const float* __restrict__ bp,
                                                 const float* __restrict__ nmg,
                                                 const float* __restrict__ nmb,
                                                 float* __restrict__ h,
                                                 float* __restrict__ mu,
                                                 float* __restrict__ rstd) {
    __shared__ float shs[16][DSZ];     // 4 KB
    __shared__ float swp[16][DMODEL];  // 32 KB
    int wv = threadIdx.x >> 6;
    int lane = threadIdx.x & 63;
    int tok0 = blockIdx.x * 16;

    {
        const float4* src = (const float4*)(hs + (size_t)tok0 * DSZ);
        ((float4*)&shs[0][0])[threadIdx.x] = src[threadIdx.x];
    }
    __syncthreads();

    float acc[4][8] = {};
    for (int k0 = 0; k0 < DSZ; k0 += 16) {
        const float4* src = (const float4*)(wp + (size_t)k0 * DMODEL);
#pragma unroll
        for (int i = 0; i < 8; i++)
            ((float4*)&swp[0][0])[threadIdx.x + i * 256] = src[threadIdx.x + i * 256];
        __syncthreads();
#pragma unroll
        for (int k = 0; k < 16; k++) {
            float bv[8];
#pragma unroll
            for (int j = 0; j < 8; j++) bv[j] = swp[k][lane + 64 * j];
#pragma unroll
            for (int t = 0; t < 4; t++) {
                float av = shs[wv * 4 + t][k0 + k];
#pragma unroll
                for (int j = 0; j < 8; j++) acc[t][j] += av * bv[j];
            }
        }
        __syncthreads();
    }

#pragma unroll
    for (int t = 0; t < 4; t++) {
        int tok = tok0 + wv * 4 + t;
        float u[8];
        float s = 0.f, sq = 0.f;
#pragma unroll
        for (int j = 0; j < 8; j++) {
            int col = lane + 64 * j;
            float v = h[(size_t)tok * DMODEL + col] + acc[t][j] + bp[col];
            u[j] = v;
            s += v;
            sq += v * v;
        }
#pragma unroll
        for (int o = 32; o > 0; o >>= 1) {
            s += __shfl_xor(s, o, 64);
            sq += __shfl_xor(sq, o, 64);
        }
        float mean = s * (1.f / DMODEL);
        float var = sq * (1.f / DMODEL) - mean * mean;
        float rs = rsqrtf(var + 1e-5f);
        float s2 = 0.f, sq2 = 0.f;
#pragma unroll
        for (int j = 0; j < 8; j++) {
            int col = lane + 64 * j;
            float v = (u[j] - mean) * rs * nmg[col] + nmb[col];
            h[(size_t)tok * DMODEL + col] = v;
            s2 += v;
            sq2 += v * v;
        }
#pragma unroll
        for (int o = 32; o > 0; o >>= 1) {
            s2 += __shfl_xor(s2, o, 64);
            sq2 += __shfl_xor(sq2, o, 64);
        }
        if (lane == 0) {
            float m2 = s2 * (1.f / DMODEL);
            float v2 = sq2 * (1.f / DMODEL) - m2 * m2;
            mu[tok] = m2;
            rstd[tok] = rsqrtf(v2 + 1e-5f);
        }
    }
}

// ---------------- heads on h[:, -1, :] ----------------
__global__ __launch_bounds__(64) void heads_k(const float* __restrict__ h,
                                              const float* hd15_w, const float* hd15_b,
                                              const float* hd30_w, const float* hd30_b,
                                              const float* hv_w, const float* hv_b,
                                              const float* hreg_w, const float* hreg_b,
                                              const float* hrng_w, const float* hrng_b,
                                              float* __restrict__ out) {
    int b = blockIdx.x;
    int lane = threadIdx.x;
    __shared__ float row[DMODEL];
    const float* hp = h + (size_t)(b * SEQ + SEQ - 1) * DMODEL;
#pragma unroll
    for (int i = 0; i < 8; i++) row[lane + 64 * i] = hp[lane + 64 * i];
    __syncthreads();
#pragma unroll
    for (int i = 0; i < 8; i++) out[448 + b * DMODEL + lane + 64 * i] = row[lane + 64 * i];
    if (lane < 14) {
        const float* w; const float* bb;
        int ncol, j, off;
        if (lane == 0)      { w = hd15_w; bb = hd15_b; ncol = 1; j = 0;         off = 0 + b; }
        else if (lane == 1) { w = hd30_w; bb = hd30_b; ncol = 1; j = 0;         off = 32 + b; }
        else if (lane < 5)  { j = lane - 2;  w = hv_w;   bb = hv_b;   ncol = 3; off = 64 + b * 3 + j; }
        else if (lane < 11) { j = lane - 5;  w = hreg_w; bb = hreg_b; ncol = 6; off = 160 + b * 6 + j; }
        else                { j = lane - 11; w = hrng_w; bb = hrng_b; ncol = 3; off = 352 + b * 3 + j; }
        float s = bb[j];
        for (int k = 0; k < DMODEL; k++) s += row[k] * w[k * ncol + j];
        out[off] = s;
    }
}

extern "C" void kernel_launch(void* const* d_in, const int* in_sizes, int n_in,
                              void* d_out, int out_size, void* d_ws, size_t ws_size,
                              hipStream_t stream) {
    (void)in_sizes; (void)n_in; (void)out_size; (void)ws_size;
    const float* x      = (const float*)d_in[0];
    const int*   rid    = (const int*)d_in[1];
    const float* emb    = (const float*)d_in[2];
    const float* grn_w1 = (const float*)d_in[3];
    const float* grn_b1 = (const float*)d_in[4];
    const float* grn_w2 = (const float*)d_in[5];
    const float* grn_b2 = (const float*)d_in[6];
    const float* in_w   = (const float*)d_in[7];
    const float* in_b   = (const float*)d_in[8];
    const float* ln_g   = (const float*)d_in[9];
    const float* ln_b   = (const float*)d_in[10];
    const float* wi     = (const float*)d_in[11];
    const float* bi     = (const float*)d_in[12];
    const float* wf     = (const float*)d_in[13];
    const float* bf     = (const float*)d_in[14];
    const float* wz     = (const float*)d_in[15];
    const float* bz     = (const float*)d_in[16];
    const float* wo     = (const float*)d_in[17];
    const float* bo     = (const float*)d_in[18];
    const float* wp     = (const float*)d_in[19];
    const float* bp     = (const float*)d_in[20];
    const float* nm_g   = (const float*)d_in[21];
    const float* nm_b   = (const float*)d_in[22];

    float* out = (float*)d_out;
    float* ws = (float*)d_ws;

    // workspace layout (floats):
    // [0, 33554432)                 h / hidden alias
    // [33554432, 56492032)          weights (GRN phase) -> gates(16.7M)+hs(4.2M)+scan scratch
    // [56492032, 56623104)          mu, rstd
    float* h      = ws;
    float* hidden = ws;
    float* wbuf   = ws + 33554432;
    float* gates  = wbuf;
    float* hsbuf  = wbuf + 16777216;             // 50331648
    float* aggF   = ws + 54525952;               // 32*32*64 = 65536 each
    float* aggL   = aggF + 65536;
    float* aggS   = aggL + 65536;
    float* stM    = aggS + 65536;
    float* stC    = stM + 65536;
    float* mu     = wbuf + 22937600;             // 56492032
    float* rstd   = mu + 65536;

    GemmArgs a = {};
    a.x = x; a.rid = rid; a.emb = emb;

    // GEMM 0: hidden = elu(concat(x, emb[rid]) @ grn_w1 + grn_b1)
    a.B = grn_w1; a.bias = grn_b1; a.C = hidden; a.K = KCOMB; a.N = DMODEL;
    gemm_k<0><<<dim3(8, MTOK / 64), 256, 0, stream>>>(a);

    // GEMM 1: logits = hidden @ grn_w2 + grn_b2
    a.A = hidden; a.B = grn_w2; a.bias = grn_b2; a.C = wbuf; a.K = DMODEL; a.N = NFEAT;
    gemm_k<1><<<dim3(6, MTOK / 64), 256, 0, stream>>>(a);

    // softmax in place + emit weights[:, -1, :]
    softmax_k<<<MTOK / 4, 256, 0, stream>>>(wbuf, out + 16832);

    // GEMM 2: h = (x * weights) @ in_w + in_b
    a.wgt = wbuf; a.B = in_w; a.bias = in_b; a.C = h; a.K = NFEAT; a.N = DMODEL;
    gemm_k<2><<<dim3(8, MTOK / 64), 256, 0, stream>>>(a);

    // LN stats for layer 0 (later layers get stats from outproj epilogue)
    ln_stats_k<<<MTOK / 4, 256, 0, stream>>>(h, mu, rstd);

    for (int l = 0; l < NLAYER; l++) {
        GemmArgs g = {};
        g.A = h; g.K = DMODEL; g.N = 256; g.C = gates;
        g.mu = mu; g.rstd = rstd;
        g.lng = ln_g + l * DMODEL; g.lnb = ln_b + l * DMODEL;
        g.B  = wi + (size_t)l * DMODEL * DSZ; g.bias = bi + l * DSZ;
        g.B1 = wf + (size_t)l * DMODEL * DSZ; g.bi1  = bf + l * DSZ;
        g.B2 = wz + (size_t)l * DMODEL * DSZ; g.bi2  = bz + l * DSZ;
        g.B3 = wo + (size_t)l * DMODEL * DSZ; g.bi3  = bo + l * DSZ;
        gemm_k<3><<<dim3(4, MTOK / 64), 256, 0, stream>>>(g);

        // chunked parallel scan
        seg_agg_k<<<BATCH * 8, 256, 0, stream>>>(gates, aggF, aggL, aggS);
        chunk_scan_k<<<BATCH, 64, 0, stream>>>(aggF, aggL, aggS, stM, stC);
        replay_k<<<BATCH * 8, 256, 0, stream>>>(gates, stM, stC, hsbuf);

        outproj_k<<<MTOK / 16, 256, 0, stream>>>(hsbuf,
                                                 wp + (size_t)l * DSZ * DMODEL,
                                                 bp + l * DMODEL,
                                                 nm_g + l * DMODEL,
                                                 nm_b + l * DMODEL,
                                                 h, mu, rstd);
    }

    heads_k<<<BATCH, 64, 0, stream>>>(h,
                                      (const float*)d_in[23], (const float*)d_in[24],
                                      (const float*)d_in[25], (const float*)d_in[26],
                                      (const float*)d_in[27], (const float*)d_in[28],
                                      (const float*)d_in[29], (const float*)d_in[30],
                                      (const float*)d_in[31], (const float*)d_in[32],
                                      out);
}

// Round 4
// 1445.013 us; speedup vs baseline: 4.0871x; 2.5618x over previous
//
#include <hip/hip_runtime.h>
#include <cmath>

#define NFEAT 350
#define DMODEL 512
#define NLAYER 4
#define DSZ 64
#define REG_E 32
#define BATCH 32
#define SEQ 2048
#define MTOK (BATCH * SEQ)      // 65536
#define CLAMP_V 20.0f

#define CHUNK 64
#define NCHUNK (SEQ / CHUNK)    // 32

typedef short bf16x8 __attribute__((ext_vector_type(8)));
typedef float f32x4 __attribute__((ext_vector_type(4)));

__device__ __forceinline__ unsigned short f2b(float v) {
    union { float f; unsigned int u; } x; x.f = v;
    unsigned int r = x.u + 0x7fffu + ((x.u >> 16) & 1u);
    return (unsigned short)(r >> 16);
}
__device__ __forceinline__ float b2f(unsigned short u) {
    union { unsigned int i; float f; } x; x.i = ((unsigned int)u) << 16;
    return x.f;
}
__device__ __forceinline__ unsigned int pack2(float a, float b) {
    return ((unsigned int)f2b(b) << 16) | f2b(a);
}

// ---------------- weight preconvert: dst[n][k] = bf16(src[k][n]), zero-padded ----------------
__global__ __launch_bounds__(256) void tconv_k(const float* __restrict__ src,
                                               unsigned short* __restrict__ dst,
                                               int K, int N, int Kpad) {
    int k = blockIdx.x * 256 + threadIdx.x;
    int n = blockIdx.y;
    if (k >= Kpad) return;
    float v = (k < K && n < N) ? src[(size_t)k * N + n] : 0.f;
    dst[(size_t)n * Kpad + k] = f2b(v);
}

// gates weights: z = l*4+g; src [512][64] -> dst[z][64 n][512 k]
__global__ __launch_bounds__(256) void tconv_g_k(const float* __restrict__ wi,
                                                 const float* __restrict__ wf,
                                                 const float* __restrict__ wz,
                                                 const float* __restrict__ wo,
                                                 unsigned short* __restrict__ dst) {
    int k = blockIdx.x * 256 + threadIdx.x;
    int n = blockIdx.y;
    int z = blockIdx.z;
    int l = z >> 2, g = z & 3;
    const float* src = (g == 0 ? wi : g == 1 ? wf : g == 2 ? wz : wo) + (size_t)l * DMODEL * DSZ;
    dst[(size_t)z * 32768 + (size_t)n * 512 + k] = f2b(src[(size_t)k * DSZ + n]);
}

__global__ __launch_bounds__(1024) void gbias_k(const float* bi, const float* bf_,
                                                const float* bz, const float* bo,
                                                float* __restrict__ gbias) {
    int t = threadIdx.x;                 // 1024 = L*256
    int l = t >> 8, r = t & 255, g = r >> 6, e = r & 63;
    const float* s = (g == 0 ? bi : g == 1 ? bf_ : g == 2 ? bz : bo);
    gbias[t] = s[l * 64 + e];
}

// ---------------- xc = bf16(concat(x, emb[rid], 0)) [MTOK][384] ----------------
__global__ __launch_bounds__(256) void build_xc_k(const float* __restrict__ x,
                                                  const int* __restrict__ rid,
                                                  const float* __restrict__ emb,
                                                  unsigned short* __restrict__ xc) {
    int i = blockIdx.x * 256 + threadIdx.x;      // MTOK*192
    int m = i / 192, p = i - m * 192;
    int k = p * 2;
    float a = 0.f, b = 0.f;
    if (k < 350) {
        const float2 v = *(const float2*)(x + (size_t)m * NFEAT + k);
        a = v.x; b = v.y;
    } else if (k < 382) {
        int r = rid[m];
        const float2 v = *(const float2*)(emb + r * REG_E + (k - 350));
        a = v.x; b = v.y;
    }
    ((unsigned int*)xc)[(size_t)m * 192 + p] = pack2(a, b);
}

// ---------------- MFMA GEMM: C = epi(A @ Bt^T' + bias) ----------------
// ALD 0: A bf16 [M][lda], direct 16B staging.
// ALD 1: A f32 [M][lda]; stage LN(A)= (a-mu[row])*rstd[row]*lng[k]+lnb[k] -> bf16.
// Bt [Npad][ldb] bf16 (row n = column n of B, k-contiguous).
// Tile 128x128x32, 256 threads = 4 waves (2x2 of 64x64).
// EPI 0: elu -> bf16 | 1: none -> bf16 | 2: gate act by n>>6 -> f32 | 3: none -> f32
template <int ALD, int EPI>
__global__ __launch_bounds__(256) void mgemm_k(const unsigned short* __restrict__ Ab,
                                               const float* __restrict__ Af,
                                               const unsigned short* __restrict__ Bt,
                                               const float* __restrict__ bias,
                                               float* __restrict__ Cf,
                                               unsigned short* __restrict__ Cb,
                                               const float* __restrict__ muA,
                                               const float* __restrict__ rstdA,
                                               const float* __restrict__ lng,
                                               const float* __restrict__ lnb,
                                               int lda, int ldb, int K, int N, int ldc) {
    __shared__ unsigned short As[128][40];   // 80B row stride: 16B-aligned, 2-way banks (free)
    __shared__ unsigned short Bs[128][40];
    const int tid = threadIdx.x;
    const int lane = tid & 63;
    const int wave = tid >> 6;
    const int l15 = lane & 15;
    const int quad = lane >> 4;
    const int wm = (wave >> 1) * 64;
    const int wn = (wave & 1) * 64;
    const size_t m0 = (size_t)blockIdx.y * 128;
    const int n0 = blockIdx.x * 128;

    const int sr = tid >> 2;                 // 0..63
    const int ku = tid & 3;                  // k-unit (8 elements)

    const unsigned short* Br0 = Bt + ((size_t)(n0 + sr)) * ldb + ku * 8;
    const unsigned short* Br1 = Br0 + (size_t)64 * ldb;

    const unsigned short* Ar0 = nullptr;
    const unsigned short* Ar1 = nullptr;
    const float* Fr0 = nullptr;
    const float* Fr1 = nullptr;
    float mu0 = 0.f, rs0 = 0.f, mu1 = 0.f, rs1 = 0.f;
    if (ALD == 0) {
        Ar0 = Ab + (m0 + sr) * (size_t)lda + ku * 8;
        Ar1 = Ar0 + (size_t)64 * lda;
    } else {
        Fr0 = Af + (m0 + sr) * (size_t)lda + ku * 8;
        Fr1 = Fr0 + (size_t)64 * lda;
        mu0 = muA[m0 + sr];   rs0 = rstdA[m0 + sr];
        mu1 = muA[m0 + sr + 64]; rs1 = rstdA[m0 + sr + 64];
    }

    f32x4 acc[4][4] = {};

    for (int k0 = 0; k0 < K; k0 += 32) {
        if (ALD == 0) {
            *(uint4*)&As[sr][ku * 8]      = *(const uint4*)(Ar0 + k0);
            *(uint4*)&As[sr + 64][ku * 8] = *(const uint4*)(Ar1 + k0);
        } else {
            float4 g0 = *(const float4*)(lng + k0 + ku * 8);
            float4 g1 = *(const float4*)(lng + k0 + ku * 8 + 4);
            float4 c0 = *(const float4*)(lnb + k0 + ku * 8);
            float4 c1 = *(const float4*)(lnb + k0 + ku * 8 + 4);
            {
                float4 v0 = *(const float4*)(Fr0 + k0);
                float4 v1 = *(const float4*)(Fr0 + k0 + 4);
                uint4 w;
                w.x = pack2((v0.x - mu0) * rs0 * g0.x + c0.x, (v0.y - mu0) * rs0 * g0.y + c0.y);
                w.y = pack2((v0.z - mu0) * rs0 * g0.z + c0.z, (v0.w - mu0) * rs0 * g0.w + c0.w);
                w.z = pack2((v1.x - mu0) * rs0 * g1.x + c1.x, (v1.y - mu0) * rs0 * g1.y + c1.y);
                w.w = pack2((v1.z - mu0) * rs0 * g1.z + c1.z, (v1.w - mu0) * rs0 * g1.w + c1.w);
                *(uint4*)&As[sr][ku * 8] = w;
            }
            {
                float4 v0 = *(const float4*)(Fr1 + k0);
                float4 v1 = *(const float4*)(Fr1 + k0 + 4);
                uint4 w;
                w.x = pack2((v0.x - mu1) * rs1 * g0.x + c0.x, (v0.y - mu1) * rs1 * g0.y + c0.y);
                w.y = pack2((v0.z - mu1) * rs1 * g0.z + c0.z, (v0.w - mu1) * rs1 * g0.w + c0.w);
                w.z = pack2((v1.x - mu1) * rs1 * g1.x + c1.x, (v1.y - mu1) * rs1 * g1.y + c1.y);
                w.w = pack2((v1.z - mu1) * rs1 * g1.z + c1.z, (v1.w - mu1) * rs1 * g1.w + c1.w);
                *(uint4*)&As[sr + 64][ku * 8] = w;
            }
        }
        *(uint4*)&Bs[sr][ku * 8]      = *(const uint4*)(Br0 + k0);
        *(uint4*)&Bs[sr + 64][ku * 8] = *(const uint4*)(Br1 + k0);
        __syncthreads();
        bf16x8 af[4], bf[4];
#pragma unroll
        for (int mt = 0; mt < 4; mt++)
            af[mt] = *(const bf16x8*)&As[wm + mt * 16 + l15][quad * 8];
#pragma unroll
        for (int nt = 0; nt < 4; nt++)
            bf[nt] = *(const bf16x8*)&Bs[wn + nt * 16 + l15][quad * 8];
#pragma unroll
        for (int mt = 0; mt < 4; mt++)
#pragma unroll
            for (int nt = 0; nt < 4; nt++)
                acc[mt][nt] = __builtin_amdgcn_mfma_f32_16x16x32_bf16(af[mt], bf[nt], acc[mt][nt], 0, 0, 0);
        __syncthreads();
    }

#pragma unroll
    for (int mt = 0; mt < 4; mt++) {
        int gmb = wm + mt * 16 + quad * 4;
#pragma unroll
        for (int nt = 0; nt < 4; nt++) {
            int gn = n0 + wn + nt * 16 + l15;
            if (gn < N) {
                float bv = bias[gn];
#pragma unroll
                for (int r = 0; r < 4; r++) {
                    size_t gm = m0 + gmb + r;
                    float v = acc[mt][nt][r] + bv;
                    if (EPI == 0) {
                        v = v > 0.f ? v : expm1f(v);
                        Cb[gm * (size_t)ldc + gn] = f2b(v);
                    } else if (EPI == 1) {
                        Cb[gm * (size_t)ldc + gn] = f2b(v);
                    } else if (EPI == 2) {
                        int g = gn >> 6;
                        if (g < 2) v = fminf(fmaxf(v, -CLAMP_V), CLAMP_V);
                        else if (g == 2) v = tanhf(v);
                        else v = 1.f / (1.f + expf(-v));
                        Cf[gm * (size_t)ldc + gn] = v;
                    } else {
                        Cf[gm * (size_t)ldc + gn] = v;
                    }
                }
            }
        }
    }
}

// ---------------- softmax over bf16 logits; writes xw=w*x in-place into xc; emits w last row ----------------
__global__ __launch_bounds__(256) void softmax_xw_k(const unsigned short* __restrict__ logits,
                                                    unsigned short* __restrict__ xc,
                                                    float* __restrict__ out_wlast) {
    int tok = blockIdx.x * 4 + (threadIdx.x >> 6);
    int lane = threadIdx.x & 63;
    const unsigned short* lr = logits + (size_t)tok * NFEAT;
    unsigned short* xr = xc + (size_t)tok * 384;
    float v[6];
    float mx = -1e30f;
#pragma unroll
    for (int i = 0; i < 6; i++) {
        int idx = lane + 64 * i;
        v[i] = (idx < NFEAT) ? b2f(lr[idx]) : -1e30f;
        mx = fmaxf(mx, v[i]);
    }
#pragma unroll
    for (int o = 32; o > 0; o >>= 1) mx = fmaxf(mx, __shfl_xor(mx, o, 64));
    float s = 0.f;
#pragma unroll
    for (int i = 0; i < 6; i++) { v[i] = expf(v[i] - mx); s += v[i]; }
#pragma unroll
    for (int o = 32; o > 0; o >>= 1) s += __shfl_xor(s, o, 64);
    float inv = 1.f / s;
    bool last = ((tok & (SEQ - 1)) == SEQ - 1);
    int b = tok >> 11;
#pragma unroll
    for (int i = 0; i < 6; i++) {
        int idx = lane + 64 * i;
        if (idx < NFEAT) {
            float w = v[i] * inv;
            xr[idx] = f2b(w * b2f(xr[idx]));
            if (last) out_wlast[b * NFEAT + idx] = w;
        } else if (idx < 352) {
            xr[idx] = 0;   // kill emb residue: GEMM2 reads K=352
        }
    }
}

// ---------------- per-token LN stats (mu, rstd) on f32 h ----------------
__global__ __launch_bounds__(256) void ln_stats_k(const float* __restrict__ h,
                                                  float* __restrict__ mu,
                                                  float* __restrict__ rstd) {
    int tok = blockIdx.x * 4 + (threadIdx.x >> 6);
    int lane = threadIdx.x & 63;
    const float* row = h + (size_t)tok * DMODEL;
    float s = 0.f, sq = 0.f;
#pragma unroll
    for (int i = 0; i < 8; i++) {
        float v = row[lane + 64 * i];
        s += v;
        sq += v * v;
    }
#pragma unroll
    for (int o = 32; o > 0; o >>= 1) {
        s += __shfl_xor(s, o, 64);
        sq += __shfl_xor(sq, o, 64);
    }
    if (lane == 0) {
        float m = s * (1.f / DMODEL);
        float var = sq * (1.f / DMODEL) - m * m;
        mu[tok] = m;
        rstd[tok] = rsqrtf(var + 1e-5f);
    }
}

// ================= chunked parallel scan =================
__global__ __launch_bounds__(256) void seg_agg_k(const float* __restrict__ gates,
                                                 float* __restrict__ aggF,
                                                 float* __restrict__ aggL,
                                                 float* __restrict__ aggS) {
    int b = blockIdx.x >> 3;
    int cg = blockIdx.x & 7;
    int chunk = cg * 4 + (threadIdx.x >> 6);
    int e = threadIdx.x & 63;
    const float* gp = gates + ((size_t)b * SEQ + (size_t)chunk * CHUNK) * 256;
    float F = 0.f, L = -1e30f, s = 0.f;
#pragma unroll 4
    for (int t = 0; t < CHUNK; t++) {
        const float* q = gp + (size_t)t * 256;
        float li = q[e], lf = q[64 + e], z = q[128 + e];
        float Ln = fmaxf(L + lf, li);
        s = expf(L + lf - Ln) * s + expf(li - Ln) * z;
        L = Ln;
        F += lf;
    }
    int idx = (b * NCHUNK + chunk) * 64 + e;
    aggF[idx] = F; aggL[idx] = L; aggS[idx] = s;
}

__global__ __launch_bounds__(64) void chunk_scan_k(const float* __restrict__ aggF,
                                                   const float* __restrict__ aggL,
                                                   const float* __restrict__ aggS,
                                                   float* __restrict__ stM,
                                                   float* __restrict__ stC) {
    int b = blockIdx.x;
    int e = threadIdx.x;
    float m = 0.f, c = 0.f;
    for (int k = 0; k < NCHUNK; k++) {
        int idx = (b * NCHUNK + k) * 64 + e;
        stM[idx] = m; stC[idx] = c;
        float F = aggF[idx], L = aggL[idx], s = aggS[idx];
        float mn = fmaxf(m + F, L);
        c = expf(m + F - mn) * c + expf(L - mn) * s;
        m = mn;
    }
}

__global__ __launch_bounds__(256) void replay_k(const float* __restrict__ gates,
                                                const float* __restrict__ stM,
                                                const float* __restrict__ stC,
                                                float* __restrict__ hs) {
    int b = blockIdx.x >> 3;
    int cg = blockIdx.x & 7;
    int chunk = cg * 4 + (threadIdx.x >> 6);
    int e = threadIdx.x & 63;
    int s0 = chunk * CHUNK;
    const float* gp = gates + ((size_t)b * SEQ + s0) * 256;
    float* hp = hs + ((size_t)b * SEQ + s0) * DSZ;
    int idx = (b * NCHUNK + chunk) * 64 + e;
    float m = stM[idx], c = stC[idx];
#pragma unroll 4
    for (int t = 0; t < CHUNK; t++) {
        const float* q = gp + (size_t)t * 256;
        float li = q[e], lf = q[64 + e], z = q[128 + e], o = q[192 + e];
        float mlf = m + lf;
        float mn = fmaxf(mlf, li);
        c = expf(mlf - mn) * c + expf(li - mn) * z;
        m = mn;
        hp[(size_t)t * DSZ + e] = o * tanhf(c);
    }
}

// ---------------- out-proj + residual + LN (h f32 in-place) + mu/rstd for next layer ----------------
__global__ __launch_bounds__(256) void outproj_k(const float* __restrict__ hs,
                                                 const float* __restrict__ wp,
                                                 const float* __restrict__ bp,
                                                 const float* __restrict__ nmg,
                                                 const float* __restrict__ nmb,
                                                 float* __restrict__ h,
                                                 float* __restrict__ mu,
                                                 float* __restrict__ rstd) {
    __shared__ float shs[16][DSZ];
    __shared__ float swp[16][DMODEL];
    int wv = threadIdx.x >> 6;
    int lane = threadIdx.x & 63;
    int tok0 = blockIdx.x * 16;

    {
        const float4* src = (const float4*)(hs + (size_t)tok0 * DSZ);
        ((float4*)&shs[0][0])[threadIdx.x] = src[threadIdx.x];
    }
    __syncthreads();

    float acc[4][8] = {};
    for (int k0 = 0; k0 < DSZ; k0 += 16) {
        const float4* src = (const float4*)(wp + (size_t)k0 * DMODEL);
#pragma unroll
        for (int i = 0; i < 8; i++)
            ((float4*)&swp[0][0])[threadIdx.x + i * 256] = src[threadIdx.x + i * 256];
        __syncthreads();
#pragma unroll
        for (int k = 0; k < 16; k++) {
            float bv[8];
#pragma unroll
            for (int j = 0; j < 8; j++) bv[j] = swp[k][lane + 64 * j];
#pragma unroll
            for (int t = 0; t < 4; t++) {
                float av = shs[wv * 4 + t][k0 + k];
#pragma unroll
                for (int j = 0; j < 8; j++) acc[t][j] += av * bv[j];
            }
        }
        __syncthreads();
    }

#pragma unroll
    for (int t = 0; t < 4; t++) {
        int tok = tok0 + wv * 4 + t;
        float u[8];
        float s = 0.f, sq = 0.f;
#pragma unroll
        for (int j = 0; j < 8; j++) {
            int col = lane + 64 * j;
            float v = h[(size_t)tok * DMODEL + col] + acc[t][j] + bp[col];
            u[j] = v;
            s += v; sq += v * v;
        }
#pragma unroll
        for (int o = 32; o > 0; o >>= 1) { s += __shfl_xor(s, o, 64); sq += __shfl_xor(sq, o, 64); }
        float mean = s * (1.f / DMODEL);
        float var = sq * (1.f / DMODEL) - mean * mean;
        float rs = rsqrtf(var + 1e-5f);
        float s2 = 0.f, sq2 = 0.f;
#pragma unroll
        for (int j = 0; j < 8; j++) {
            int col = lane + 64 * j;
            float v = (u[j] - mean) * rs * nmg[col] + nmb[col];
            h[(size_t)tok * DMODEL + col] = v;
            s2 += v; sq2 += v * v;
        }
#pragma unroll
        for (int o = 32; o > 0; o >>= 1) { s2 += __shfl_xor(s2, o, 64); sq2 += __shfl_xor(sq2, o, 64); }
        if (lane == 0) {
            float m2 = s2 * (1.f / DMODEL);
            float v2 = sq2 * (1.f / DMODEL) - m2 * m2;
            mu[tok] = m2;
            rstd[tok] = rsqrtf(v2 + 1e-5f);
        }
    }
}

// ---------------- heads on h[:, -1, :] (f32) ----------------
__global__ __launch_bounds__(64) void heads_k(const float* __restrict__ h,
                                              const float* hd15_w, const float* hd15_b,
                                              const float* hd30_w, const float* hd30_b,
                                              const float* hv_w, const float* hv_b,
                                              const float* hreg_w, const float* hreg_b,
                                              const float* hrng_w, const float* hrng_b,
                                              float* __restrict__ out) {
    int b = blockIdx.x;
    int lane = threadIdx.x;
    __shared__ float row[DMODEL];
    const float* hp = h + (size_t)(b * SEQ + SEQ - 1) * DMODEL;
#pragma unroll
    for (int i = 0; i < 8; i++) row[lane + 64 * i] = hp[lane + 64 * i];
    __syncthreads();
#pragma unroll
    for (int i = 0; i < 8; i++) out[448 + b * DMODEL + lane + 64 * i] = row[lane + 64 * i];
    if (lane < 14) {
        const float* w; const float* bb;
        int ncol, j, off;
        if (lane == 0)      { w = hd15_w; bb = hd15_b; ncol = 1; j = 0;         off = 0 + b; }
        else if (lane == 1) { w = hd30_w; bb = hd30_b; ncol = 1; j = 0;         off = 32 + b; }
        else if (lane < 5)  { j = lane - 2;  w = hv_w;   bb = hv_b;   ncol = 3; off = 64 + b * 3 + j; }
        else if (lane < 11) { j = lane - 5;  w = hreg_w; bb = hreg_b; ncol = 6; off = 160 + b * 6 + j; }
        else                { j = lane - 11; w = hrng_w; bb = hrng_b; ncol = 3; off = 352 + b * 3 + j; }
        float s = bb[j];
        for (int k = 0; k < DMODEL; k++) s += row[k] * w[k * ncol + j];
        out[off] = s;
    }
}

extern "C" void kernel_launch(void* const* d_in, const int* in_sizes, int n_in,
                              void* d_out, int out_size, void* d_ws, size_t ws_size,
                              hipStream_t stream) {
    (void)in_sizes; (void)n_in; (void)out_size; (void)ws_size;
    const float* x      = (const float*)d_in[0];
    const int*   rid    = (const int*)d_in[1];
    const float* emb    = (const float*)d_in[2];
    const float* grn_w1 = (const float*)d_in[3];
    const float* grn_b1 = (const float*)d_in[4];
    const float* grn_w2 = (const float*)d_in[5];
    const float* grn_b2 = (const float*)d_in[6];
    const float* in_w   = (const float*)d_in[7];
    const float* in_b   = (const float*)d_in[8];
    const float* ln_g   = (const float*)d_in[9];
    const float* ln_b   = (const float*)d_in[10];
    const float* wi     = (const float*)d_in[11];
    const float* bi     = (const float*)d_in[12];
    const float* wf     = (const float*)d_in[13];
    const float* bf_    = (const float*)d_in[14];
    const float* wz     = (const float*)d_in[15];
    const float* bz     = (const float*)d_in[16];
    const float* wo     = (const float*)d_in[17];
    const float* bo     = (const float*)d_in[18];
    const float* wp     = (const float*)d_in[19];
    const float* bp     = (const float*)d_in[20];
    const float* nm_g   = (const float*)d_in[21];
    const float* nm_b   = (const float*)d_in[22];

    float* out = (float*)d_out;
    char* W = (char*)d_ws;

    // ---- workspace layout (bytes), peak 222,138,368 < 226,492,416 proven ----
    // [0, 134217728)    h f32 [MTOK][512]
    //   steps 2-3: hidden bf16 [MTOK][512] at +0 (dead before h written)
    //   steps 3-4: logits bf16 [MTOK][350] at +67108864 (dead before h written)
    // [134217728, 218103808)  region B:
    //   steps 1-5: xc bf16 [MTOK][384] (50.3 MB)
    //   loop:      gates f32 [MTOK][256] at +0, hsbuf f32 [MTOK][64] at +67108864
    // [218103808, ...)  misc: agg scratch, mu/rstd, converted weights
    float* h               = (float*)W;
    unsigned short* hidden = (unsigned short*)W;
    unsigned short* logits = (unsigned short*)(W + 67108864);
    char* RB = W + 134217728;
    unsigned short* xc = (unsigned short*)RB;
    float* gates  = (float*)RB;
    float* hsbuf  = (float*)(RB + 67108864);
    char* RM = W + 218103808;
    float* aggF  = (float*)(RM);
    float* aggL  = (float*)(RM + 262144);
    float* aggS  = (float*)(RM + 524288);
    float* stM   = (float*)(RM + 786432);
    float* stC   = (float*)(RM + 1048576);
    float* mu    = (float*)(RM + 1310720);
    float* rstd  = (float*)(RM + 1572864);
    unsigned short* w1t  = (unsigned short*)(RM + 1835008);  // [512][384]
    unsigned short* w2t  = (unsigned short*)(RM + 2228224);  // [384][512]
    unsigned short* inwt = (unsigned short*)(RM + 2621440);  // [512][352]
    unsigned short* gwt  = (unsigned short*)(RM + 2981888);  // [16][64][512]
    float* gbias         = (float*)(RM + 4030464);           // [4][256]

    // ---- preconvert (every call; graph-safe) ----
    build_xc_k<<<MTOK * 192 / 256, 256, 0, stream>>>(x, rid, emb, xc);
    tconv_k<<<dim3(2, 512), 256, 0, stream>>>(grn_w1, w1t, 382, 512, 384);
    tconv_k<<<dim3(2, 384), 256, 0, stream>>>(grn_w2, w2t, 512, 350, 512);
    tconv_k<<<dim3(2, 512), 256, 0, stream>>>(in_w, inwt, 350, 512, 352);
    tconv_g_k<<<dim3(2, 64, 16), 256, 0, stream>>>(wi, wf, wz, wo, gwt);
    gbias_k<<<1, 1024, 0, stream>>>(bi, bf_, bz, bo, gbias);

    // GEMM0: hidden = elu(xc @ w1t^T + b1), bf16 out
    mgemm_k<0, 0><<<dim3(4, 512), 256, 0, stream>>>(xc, nullptr, w1t, grn_b1, nullptr, hidden,
                                                    nullptr, nullptr, nullptr, nullptr,
                                                    384, 384, 384, 512, 512);
    // GEMM1: logits = hidden @ w2t^T + b2, bf16 out
    mgemm_k<0, 1><<<dim3(3, 512), 256, 0, stream>>>(hidden, nullptr, w2t, grn_b2, nullptr, logits,
                                                    nullptr, nullptr, nullptr, nullptr,
                                                    512, 512, 512, 350, 350);
    // softmax + xw in-place into xc + weights last row
    softmax_xw_k<<<MTOK / 4, 256, 0, stream>>>(logits, xc, out + 16832);
    // GEMM2: h = xw @ inwt^T + in_b, f32 out
    mgemm_k<0, 3><<<dim3(4, 512), 256, 0, stream>>>(xc, nullptr, inwt, in_b, h, nullptr,
                                                    nullptr, nullptr, nullptr, nullptr,
                                                    384, 352, 352, 512, 512);
    // layer-0 LN stats
    ln_stats_k<<<MTOK / 4, 256, 0, stream>>>(h, mu, rstd);

    for (int l = 0; l < NLAYER; l++) {
        // gates = act(LN(h) @ gwt[l]^T + gbias[l]), f32 out; LN fused into A-staging
        mgemm_k<1, 2><<<dim3(2, 512), 256, 0, stream>>>(nullptr, h, gwt + (size_t)l * 131072,
                                                        gbias + l * 256, gates, nullptr,
                                                        mu, rstd,
                                                        ln_g + l * DMODEL, ln_b + l * DMODEL,
                                                        512, 512, 512, 256, 256);
        seg_agg_k<<<BATCH * 8, 256, 0, stream>>>(gates, aggF, aggL, aggS);
        chunk_scan_k<<<BATCH, 64, 0, stream>>>(aggF, aggL, aggS, stM, stC);
        replay_k<<<BATCH * 8, 256, 0, stream>>>(gates, stM, stC, hsbuf);

        outproj_k<<<MTOK / 16, 256, 0, stream>>>(hsbuf,
                                                 wp + (size_t)l * DSZ * DMODEL,
                                                 bp + l * DMODEL,
                                                 nm_g + l * DMODEL,
                                                 nm_b + l * DMODEL,
                                                 h, mu, rstd);
    }

    heads_k<<<BATCH, 64, 0, stream>>>(h,
                                      (const float*)d_in[23], (const float*)d_in[24],
                                      (const float*)d_in[25], (const float*)d_in[26],
                                      (const float*)d_in[27], (const float*)d_in[28],
                                      (const float*)d_in[29], (const float*)d_in[30],
                                      (const float*)d_in[31], (const float*)d_in[32],
                                      out);
}